// Round 10
// baseline (158.986 us; speedup 1.0000x reference)
//
#include <hip/hip_runtime.h>

#define DIMN 32
#define HD   32
#define FN   16
#define FE   8
#define NG   64
#define CAP  64          // bucket capacity (in-degree ~Poisson(16); fallback below)
#define K3T  512
#define K3W  (K3T / 64)  // 8 waves = 8 nodes per block (one node per wave)

// K1: out = relu(x @ lin0_w^T + lin0_b); zero deg/aggfb/u.
__global__ __launch_bounds__(256) void k1_out(
    const float* __restrict__ x, const float* __restrict__ lin0_w,
    const float* __restrict__ lin0_b,
    float* __restrict__ outn, float* __restrict__ aggfb, float* __restrict__ u,
    int* __restrict__ deg, int N)
{
    const int gt = blockIdx.x * 256 + threadIdx.x;
    if (gt >= N * DIMN) return;
    const int n = gt >> 5, d = gt & 31;

    float s = lin0_b[d];
    const float* xr = x + (size_t)n * FN;
    const float* wr = lin0_w + d * FN;
    #pragma unroll
    for (int j = 0; j < FN; ++j) s = fmaf(xr[j], wr[j], s);
    outn[gt] = fmaxf(s, 0.f);

    aggfb[gt] = 0.f;
    if (d == 0) deg[n] = 0;
    if (gt < NG * HD) u[gt] = 0.f;
}

// Kb: bucket edges by destination, staging VALUES (not indices):
//   outB[slot][0..31] = out[src][0..31]   (the whole source row)
//   eaB [slot][0..7]  = ea[e][0..7]
// 8 lanes per edge: lane sub handles 16B of the out row; subs 0-1 copy ea.
// The out[src] gather happens HERE, where src is available immediately from a
// coalesced ei read and TLP is per-edge (1.6M threads) -- latency is free.
// k3 then has ZERO dependent gathers. Overflow (statistically never): lane 0
// computes the message serially into aggfb.
__global__ __launch_bounds__(256) void kb_bucket(
    const int* __restrict__ ei, const float* __restrict__ ea,
    const float* __restrict__ outn, const float* __restrict__ nn_w,
    const float* __restrict__ nn_b,
    int* __restrict__ deg, float* __restrict__ eaB, float* __restrict__ outB,
    float* __restrict__ aggfb, int E)
{
    const int t = blockIdx.x * 256 + threadIdx.x;
    const int e   = t >> 3;
    const int sub = t & 7;
    if (e >= E) return;
    const int src = ei[e];
    const int dst = ei[E + e];

    int pos = 0;
    if (sub == 0) pos = atomicAdd(&deg[dst], 1);
    pos = __shfl(pos, (threadIdx.x & 63) & ~7);   // broadcast within the 8-group

    if (pos < CAP) {
        const size_t slot = (size_t)dst * CAP + pos;
        const float4 q = *(const float4*)(outn + (size_t)src * DIMN + sub * 4);
        *(float4*)(outB + slot * 32 + sub * 4) = q;
        if (sub < 2) {
            const float4 w = *(const float4*)(ea + (size_t)e * FE + sub * 4);
            *(float4*)(eaB + slot * 8 + sub * 4) = w;
        }
    } else if (sub == 0) {
        float ef[FE];
        #pragma unroll
        for (int f = 0; f < FE; ++f) ef[f] = ea[(size_t)e * FE + f];
        for (int h = 0; h < HD; ++h) {
            float m = 0.f;
            for (int d = 0; d < DIMN; ++d) {
                float wdh = nn_b[d * HD + h];
                #pragma unroll
                for (int f = 0; f < FE; ++f)
                    wdh = fmaf(ef[f], nn_w[(d * HD + h) * FE + f], wdh);
                m = fmaf(outn[(size_t)src * DIMN + d], wdh, m);
            }
            atomicAdd(aggfb + (size_t)dst * HD + h, m);
        }
    }
}

// One edge's contribution (mask already applied to o).
#define EDGE_FMA(o, a) \
    S  = (S + (o));                      \
    T0 = fmaf((o), (a).x, T0);           \
    T1 = fmaf((o), (a).y, T1);           \
    T2 = fmaf((o), (a).z, T2);           \
    T3 = fmaf((o), (a).w, T3);

// One d-slice of the contraction into accumulator A.
#define CONTRIB(DD, A) { \
    const int d_ = d0 + (DD); \
    const float4 ta_ = *(const float4*)&s_T[w * 256 + d_ * 8]; \
    const float4 tb_ = *(const float4*)&s_T[w * 256 + d_ * 8 + 4]; \
    const float2 so_ = s_SO[w * 32 + d_]; \
    const int b_ = d_ * 256 + h; \
    A = fmaf(ta_.x, s_nnw2[b_      ], A); \
    A = fmaf(ta_.y, s_nnw2[b_ +  32], A); \
    A = fmaf(ta_.z, s_nnw2[b_ +  64], A); \
    A = fmaf(ta_.w, s_nnw2[b_ +  96], A); \
    A = fmaf(tb_.x, s_nnw2[b_ + 128], A); \
    A = fmaf(tb_.y, s_nnw2[b_ + 160], A); \
    A = fmaf(tb_.z, s_nnw2[b_ + 192], A); \
    A = fmaf(tb_.w, s_nnw2[b_ + 224], A); \
    A = fmaf(so_.x, s_nnb[d_ * 32 + h], A); \
    A = fmaf(so_.y, s_rw [d_ * 32 + h], A); }

// K3: one node per wave. STREAMING edge loop: both operands (outB, eaB) read at
// addresses that are pure arithmetic in (node, j) -- no s_load->gather chain,
// all 16 loads per chunk independent and offset-immediate-folded, so the
// compiler pipelines chunk i+1 loads under chunk i FMAs. Epilogue unchanged.
__global__ __launch_bounds__(K3T, 6) void k3_gather(
    const float* __restrict__ eaB, const float* __restrict__ outB,
    const float* __restrict__ outn, const float* __restrict__ nn_w,
    const float* __restrict__ nn_b, const float* __restrict__ root_w,
    const float* __restrict__ conv_b, const int* __restrict__ deg,
    const float* __restrict__ aggfb, const int* __restrict__ batch,
    float* __restrict__ u, int N)
{
    __shared__ float  s_nnw2[DIMN * FE * HD];  // [(d*8+f)*32 + h]  32 KB
    __shared__ float  s_nnb[DIMN * HD];        // 4 KB
    __shared__ float  s_rw[DIMN * HD];         // 4 KB
    __shared__ float  s_cb[HD];
    __shared__ float  s_T[K3W * 256];          // 8 KB (per-wave T slot)
    __shared__ float2 s_SO[K3W * 32];          // 2 KB (S, out[n]) per wave
    __shared__ float  s_V[K3W * 32];           // 1 KB (per-wave node result)
    __shared__ int    s_G[K3W];

    const int tid = threadIdx.x;
    // Destination-linear staging (conflict-free LDS writes).
    for (int i = tid; i < DIMN * FE * HD; i += K3T) {
        const int d = i >> 8, f = (i >> 5) & 7, hh = i & 31;
        s_nnw2[i] = nn_w[d * 256 + hh * 8 + f];
    }
    for (int i = tid; i < DIMN * HD; i += K3T) { s_nnb[i] = nn_b[i]; s_rw[i] = root_w[i]; }
    if (tid < HD) s_cb[tid] = conv_b[tid];
    __syncthreads();

    const int l = tid & 63;
    const int h = l & 31;
    const int p = l >> 5;
    const int w = tid >> 6;
    const int n = blockIdx.x * K3W + w;   // one node per wave

    int gval = -1;
    if (n < N) {
        const int nu = __builtin_amdgcn_readfirstlane(n);
        const int dn = min(deg[nu], CAP);          // uniform -> s_load
        const float* ob = outB + (size_t)nu * CAP * 32;
        const float* eb = eaB  + (size_t)nu * CAP * 8;
        const int f0 = 4 * p;

        float T0 = 0.f, T1 = 0.f, T2 = 0.f, T3 = 0.f, S = 0.f;

        int j0 = 0;
        for (; j0 + 8 <= dn; j0 += 8) {
            const float4 a0 = *(const float4*)(eb + (size_t)(j0 + 0) * 8 + f0);
            const float4 a1 = *(const float4*)(eb + (size_t)(j0 + 1) * 8 + f0);
            const float4 a2 = *(const float4*)(eb + (size_t)(j0 + 2) * 8 + f0);
            const float4 a3 = *(const float4*)(eb + (size_t)(j0 + 3) * 8 + f0);
            const float4 a4 = *(const float4*)(eb + (size_t)(j0 + 4) * 8 + f0);
            const float4 a5 = *(const float4*)(eb + (size_t)(j0 + 5) * 8 + f0);
            const float4 a6 = *(const float4*)(eb + (size_t)(j0 + 6) * 8 + f0);
            const float4 a7 = *(const float4*)(eb + (size_t)(j0 + 7) * 8 + f0);
            const float o0 = ob[(size_t)(j0 + 0) * 32 + h];
            const float o1 = ob[(size_t)(j0 + 1) * 32 + h];
            const float o2 = ob[(size_t)(j0 + 2) * 32 + h];
            const float o3 = ob[(size_t)(j0 + 3) * 32 + h];
            const float o4 = ob[(size_t)(j0 + 4) * 32 + h];
            const float o5 = ob[(size_t)(j0 + 5) * 32 + h];
            const float o6 = ob[(size_t)(j0 + 6) * 32 + h];
            const float o7 = ob[(size_t)(j0 + 7) * 32 + h];

            EDGE_FMA(o0, a0) EDGE_FMA(o1, a1) EDGE_FMA(o2, a2) EDGE_FMA(o3, a3)
            EDGE_FMA(o4, a4) EDGE_FMA(o5, a5) EDGE_FMA(o6, a6) EDGE_FMA(o7, a7)
        }
        if (j0 < dn) {                 // masked tail batch (addresses clamped)
            const int jm = dn - 1;
            const int j1 = min(j0 + 1, jm), j2 = min(j0 + 2, jm);
            const int j3 = min(j0 + 3, jm), j4 = min(j0 + 4, jm);
            const int j5 = min(j0 + 5, jm), j6 = min(j0 + 6, jm);
            const float4 a0 = *(const float4*)(eb + (size_t)j0 * 8 + f0);
            const float4 a1 = *(const float4*)(eb + (size_t)j1 * 8 + f0);
            const float4 a2 = *(const float4*)(eb + (size_t)j2 * 8 + f0);
            const float4 a3 = *(const float4*)(eb + (size_t)j3 * 8 + f0);
            const float4 a4 = *(const float4*)(eb + (size_t)j4 * 8 + f0);
            const float4 a5 = *(const float4*)(eb + (size_t)j5 * 8 + f0);
            const float4 a6 = *(const float4*)(eb + (size_t)j6 * 8 + f0);
            const float o0 = ob[(size_t)j0 * 32 + h];
            float o1 = ob[(size_t)j1 * 32 + h];
            float o2 = ob[(size_t)j2 * 32 + h];
            float o3 = ob[(size_t)j3 * 32 + h];
            float o4 = ob[(size_t)j4 * 32 + h];
            float o5 = ob[(size_t)j5 * 32 + h];
            float o6 = ob[(size_t)j6 * 32 + h];
            o1 = (j0 + 1 <= jm) ? o1 : 0.f;
            o2 = (j0 + 2 <= jm) ? o2 : 0.f;
            o3 = (j0 + 3 <= jm) ? o3 : 0.f;
            o4 = (j0 + 4 <= jm) ? o4 : 0.f;
            o5 = (j0 + 5 <= jm) ? o5 : 0.f;
            o6 = (j0 + 6 <= jm) ? o6 : 0.f;
            EDGE_FMA(o0, a0) EDGE_FMA(o1, a1) EDGE_FMA(o2, a2) EDGE_FMA(o3, a3)
            EDGE_FMA(o4, a4) EDGE_FMA(o5, a5) EDGE_FMA(o6, a6)
        }

        // Stage T (lane l -> T[d=h, f0..f0+3]), (S, out[n,d]) for the contraction.
        *(float4*)&s_T[w * 256 + h * 8 + f0] = make_float4(T0, T1, T2, T3);
        if (p == 0) s_SO[w * 32 + h] = make_float2(S, outn[(size_t)nu * DIMN + h]);
        // Same-wave LDS write->read: lockstep + compiler lgkmcnt orders this.

        const float base = aggfb[(size_t)nu * HD + h] + s_cb[h];

        // Contraction: lane (h,p) sums its 16-d half; 4 split accumulator chains.
        float acc0 = 0.f, acc1 = 0.f, acc2 = 0.f, acc3 = 0.f;
        const int d0 = p << 4;
        #pragma unroll
        for (int dd = 0; dd < 16; dd += 4) {
            CONTRIB(dd + 0, acc0)
            CONTRIB(dd + 1, acc1)
            CONTRIB(dd + 2, acc2)
            CONTRIB(dd + 3, acc3)
        }
        float acc = (acc0 + acc1) + (acc2 + acc3);
        acc += __shfl_xor(acc, 32);              // combine the two half-wave d-halves

        const float v = fmaxf(acc + base, 0.f);
        if (p == 0) s_V[w * 32 + h] = v;
        gval = batch[nu];                        // uniform across the wave
    }
    if (l == 0) s_G[w] = gval;
    __syncthreads();

    // Block-level run-length pool over the 8 consecutive nodes (batch sorted).
    if (tid < 32) {
        float accp = 0.f;
        int   gc   = -1;
        #pragma unroll
        for (int ww = 0; ww < K3W; ++ww) {
            const int gg = s_G[ww];
            if (gg >= 0) {
                const float vv = s_V[ww * 32 + tid];
                if (gg != gc) {
                    if (gc >= 0) atomicAdd(u + (size_t)gc * HD + tid, accp);
                    gc = gg;
                    accp = vv;
                } else {
                    accp += vv;
                }
            }
        }
        if (gc >= 0) atomicAdd(u + (size_t)gc * HD + tid, accp);
    }
}

// K4: head — o = relu(u@lin1_w^T + lin1_b); out = o@lin2_w^T + lin2_b.
__global__ __launch_bounds__(64) void k4_head(
    const float* __restrict__ u, const float* __restrict__ lin1_w,
    const float* __restrict__ lin1_b, const float* __restrict__ lin2_w,
    const float* __restrict__ lin2_b, float* __restrict__ outp)
{
    const int g = threadIdx.x;
    if (g >= NG) return;

    float ur[HD];
    #pragma unroll
    for (int hh = 0; hh < HD; ++hh) ur[hh] = u[(size_t)g * HD + hh];

    float acc = lin2_b[0];
    #pragma unroll
    for (int i = 0; i < 16; ++i) {
        float o = lin1_b[i];
        #pragma unroll
        for (int hh = 0; hh < HD; ++hh)
            o = fmaf(ur[hh], lin1_w[i * HD + hh], o);
        o = fmaxf(o, 0.f);
        acc = fmaf(o, lin2_w[i], acc);
    }
    outp[g] = acc;
}

extern "C" void kernel_launch(void* const* d_in, const int* in_sizes, int n_in,
                              void* d_out, int out_size, void* d_ws, size_t ws_size,
                              hipStream_t stream)
{
    const float* x      = (const float*)d_in[0];
    const int*   ei     = (const int*)  d_in[1];
    const float* ea     = (const float*)d_in[2];
    const int*   batch  = (const int*)  d_in[3];
    const float* lin0_w = (const float*)d_in[4];
    const float* lin0_b = (const float*)d_in[5];
    const float* nn_w   = (const float*)d_in[6];
    const float* nn_b   = (const float*)d_in[7];
    const float* root_w = (const float*)d_in[8];
    const float* conv_b = (const float*)d_in[9];
    const float* lin1_w = (const float*)d_in[10];
    const float* lin1_b = (const float*)d_in[11];
    const float* lin2_w = (const float*)d_in[12];
    const float* lin2_b = (const float*)d_in[13];

    const int N = in_sizes[0] / FN;   // 12500
    const int E = in_sizes[2] / FE;   // 200000

    float* ws    = (float*)d_ws;
    float* outB  = ws;                              // N*CAP*32 floats (102.4 MB)
    float* eaB   = outB + (size_t)N * CAP * 32;     // N*CAP*8  floats (25.6 MB)
    float* outn  = eaB  + (size_t)N * CAP * 8;      // N*32
    float* aggfb = outn + (size_t)N * DIMN;         // N*32 (overflow fallback)
    float* u     = aggfb + (size_t)N * DIMN;        // 64*32
    int*   deg   = (int*)(u + (size_t)NG * HD);     // N

    const int nb1 = (N * DIMN + 255) / 256;      // 1563
    k1_out<<<nb1, 256, 0, stream>>>(x, lin0_w, lin0_b, outn, aggfb, u, deg, N);

    const int nbb = ((size_t)E * 8 + 255) / 256; // 6250
    kb_bucket<<<nbb, 256, 0, stream>>>(ei, ea, outn, nn_w, nn_b, deg, eaB, outB,
                                       aggfb, E);

    const int nb3 = (N + K3W - 1) / K3W;         // 1563 (8 nodes / block)
    k3_gather<<<nb3, K3T, 0, stream>>>(eaB, outB, outn, nn_w, nn_b, root_w, conv_b,
                                       deg, aggfb, batch, u, N);

    k4_head<<<1, 64, 0, stream>>>(u, lin1_w, lin1_b, lin2_w, lin2_b, (float*)d_out);
}

// Round 11
// 157.422 us; speedup vs baseline: 1.0099x; 1.0099x over previous
//
#include <hip/hip_runtime.h>

#define DIMN 32
#define HD   32
#define FN   16
#define FE   8
#define NG   64
#define CAP  64          // bucket capacity (in-degree ~Poisson(16); fallback below)
#define K3T  1024        // 16 waves/block -> 2 blocks/CU (LDS-capped) = 32 waves/CU
#define K3W  (K3T / 64)  // 16 nodes per block (one node per wave)

// K1: out = relu(x @ lin0_w^T + lin0_b); zero deg/aggfb/u.
__global__ __launch_bounds__(256) void k1_out(
    const float* __restrict__ x, const float* __restrict__ lin0_w,
    const float* __restrict__ lin0_b,
    float* __restrict__ outn, float* __restrict__ aggfb, float* __restrict__ u,
    int* __restrict__ deg, int N)
{
    const int gt = blockIdx.x * 256 + threadIdx.x;
    if (gt >= N * DIMN) return;
    const int n = gt >> 5, d = gt & 31;

    float s = lin0_b[d];
    const float* xr = x + (size_t)n * FN;
    const float* wr = lin0_w + d * FN;
    #pragma unroll
    for (int j = 0; j < FN; ++j) s = fmaf(xr[j], wr[j], s);
    outn[gt] = fmaxf(s, 0.f);

    aggfb[gt] = 0.f;
    if (d == 0) deg[n] = 0;
    if (gt < NG * HD) u[gt] = 0.f;
}

// Kb: bucket edges by destination, staging VALUES (not indices):
//   outB[slot][0..31] = out[src][0..31]   (the whole source row)
//   eaB [slot][0..7]  = ea[e][0..7]
// 8 lanes per edge; the out[src] gather happens here where TLP is per-edge.
// Overflow (statistically never): lane 0 computes the message into aggfb.
__global__ __launch_bounds__(256) void kb_bucket(
    const int* __restrict__ ei, const float* __restrict__ ea,
    const float* __restrict__ outn, const float* __restrict__ nn_w,
    const float* __restrict__ nn_b,
    int* __restrict__ deg, float* __restrict__ eaB, float* __restrict__ outB,
    float* __restrict__ aggfb, int E)
{
    const int t = blockIdx.x * 256 + threadIdx.x;
    const int e   = t >> 3;
    const int sub = t & 7;
    if (e >= E) return;
    const int src = ei[e];
    const int dst = ei[E + e];

    int pos = 0;
    if (sub == 0) pos = atomicAdd(&deg[dst], 1);
    pos = __shfl(pos, (threadIdx.x & 63) & ~7);   // broadcast within the 8-group

    if (pos < CAP) {
        const size_t slot = (size_t)dst * CAP + pos;
        const float4 q = *(const float4*)(outn + (size_t)src * DIMN + sub * 4);
        *(float4*)(outB + slot * 32 + sub * 4) = q;
        if (sub < 2) {
            const float4 w = *(const float4*)(ea + (size_t)e * FE + sub * 4);
            *(float4*)(eaB + slot * 8 + sub * 4) = w;
        }
    } else if (sub == 0) {
        float ef[FE];
        #pragma unroll
        for (int f = 0; f < FE; ++f) ef[f] = ea[(size_t)e * FE + f];
        for (int h = 0; h < HD; ++h) {
            float m = 0.f;
            for (int d = 0; d < DIMN; ++d) {
                float wdh = nn_b[d * HD + h];
                #pragma unroll
                for (int f = 0; f < FE; ++f)
                    wdh = fmaf(ef[f], nn_w[(d * HD + h) * FE + f], wdh);
                m = fmaf(outn[(size_t)src * DIMN + d], wdh, m);
            }
            atomicAdd(aggfb + (size_t)dst * HD + h, m);
        }
    }
}

// One edge's contribution (mask already applied to o).
#define EDGE_FMA(o, a) \
    S  = (S + (o));                      \
    T0 = fmaf((o), (a).x, T0);           \
    T1 = fmaf((o), (a).y, T1);           \
    T2 = fmaf((o), (a).z, T2);           \
    T3 = fmaf((o), (a).w, T3);

// One d-slice of the contraction into accumulator A.
#define CONTRIB(DD, A) { \
    const int d_ = d0 + (DD); \
    const float4 ta_ = *(const float4*)&s_T[w * 256 + d_ * 8]; \
    const float4 tb_ = *(const float4*)&s_T[w * 256 + d_ * 8 + 4]; \
    const float2 so_ = s_SO[w * 32 + d_]; \
    const int b_ = d_ * 256 + h; \
    A = fmaf(ta_.x, s_nnw2[b_      ], A); \
    A = fmaf(ta_.y, s_nnw2[b_ +  32], A); \
    A = fmaf(ta_.z, s_nnw2[b_ +  64], A); \
    A = fmaf(ta_.w, s_nnw2[b_ +  96], A); \
    A = fmaf(tb_.x, s_nnw2[b_ + 128], A); \
    A = fmaf(tb_.y, s_nnw2[b_ + 160], A); \
    A = fmaf(tb_.z, s_nnw2[b_ + 192], A); \
    A = fmaf(tb_.w, s_nnw2[b_ + 224], A); \
    A = fmaf(so_.x, s_nnb[d_ * 32 + h], A); \
    A = fmaf(so_.y, s_rw [d_ * 32 + h], A); }

// K3: one node per wave, 16 waves per 1024-thread block.
// ONLY change vs R10: block size 512 -> 1024. LDS/block = 63.7 KB -> 2
// blocks/CU -> 32 waves/CU (was 24): +33% TLP for the same per-wave code,
// and half the weight-staging phases (782 blocks vs 1563).
__global__ __launch_bounds__(K3T) void k3_gather(
    const float* __restrict__ eaB, const float* __restrict__ outB,
    const float* __restrict__ outn, const float* __restrict__ nn_w,
    const float* __restrict__ nn_b, const float* __restrict__ root_w,
    const float* __restrict__ conv_b, const int* __restrict__ deg,
    const float* __restrict__ aggfb, const int* __restrict__ batch,
    float* __restrict__ u, int N)
{
    __shared__ float  s_nnw2[DIMN * FE * HD];  // [(d*8+f)*32 + h]  32 KB
    __shared__ float  s_nnb[DIMN * HD];        // 4 KB
    __shared__ float  s_rw[DIMN * HD];         // 4 KB
    __shared__ float  s_cb[HD];
    __shared__ float  s_T[K3W * 256];          // 16 KB (per-wave T slot)
    __shared__ float2 s_SO[K3W * 32];          // 4 KB (S, out[n]) per wave
    __shared__ float  s_V[K3W * 32];           // 2 KB (per-wave node result)
    __shared__ int    s_G[K3W];

    const int tid = threadIdx.x;
    // Destination-linear staging (conflict-free LDS writes).
    for (int i = tid; i < DIMN * FE * HD; i += K3T) {
        const int d = i >> 8, f = (i >> 5) & 7, hh = i & 31;
        s_nnw2[i] = nn_w[d * 256 + hh * 8 + f];
    }
    for (int i = tid; i < DIMN * HD; i += K3T) { s_nnb[i] = nn_b[i]; s_rw[i] = root_w[i]; }
    if (tid < HD) s_cb[tid] = conv_b[tid];
    __syncthreads();

    const int l = tid & 63;
    const int h = l & 31;
    const int p = l >> 5;
    const int w = tid >> 6;
    const int n = blockIdx.x * K3W + w;   // one node per wave

    int gval = -1;
    if (n < N) {
        const int nu = __builtin_amdgcn_readfirstlane(n);
        const int dn = min(deg[nu], CAP);          // uniform -> s_load
        const float* ob = outB + (size_t)nu * CAP * 32;
        const float* eb = eaB  + (size_t)nu * CAP * 8;
        const int f0 = 4 * p;

        float T0 = 0.f, T1 = 0.f, T2 = 0.f, T3 = 0.f, S = 0.f;

        int j0 = 0;
        for (; j0 + 8 <= dn; j0 += 8) {
            const float4 a0 = *(const float4*)(eb + (size_t)(j0 + 0) * 8 + f0);
            const float4 a1 = *(const float4*)(eb + (size_t)(j0 + 1) * 8 + f0);
            const float4 a2 = *(const float4*)(eb + (size_t)(j0 + 2) * 8 + f0);
            const float4 a3 = *(const float4*)(eb + (size_t)(j0 + 3) * 8 + f0);
            const float4 a4 = *(const float4*)(eb + (size_t)(j0 + 4) * 8 + f0);
            const float4 a5 = *(const float4*)(eb + (size_t)(j0 + 5) * 8 + f0);
            const float4 a6 = *(const float4*)(eb + (size_t)(j0 + 6) * 8 + f0);
            const float4 a7 = *(const float4*)(eb + (size_t)(j0 + 7) * 8 + f0);
            const float o0 = ob[(size_t)(j0 + 0) * 32 + h];
            const float o1 = ob[(size_t)(j0 + 1) * 32 + h];
            const float o2 = ob[(size_t)(j0 + 2) * 32 + h];
            const float o3 = ob[(size_t)(j0 + 3) * 32 + h];
            const float o4 = ob[(size_t)(j0 + 4) * 32 + h];
            const float o5 = ob[(size_t)(j0 + 5) * 32 + h];
            const float o6 = ob[(size_t)(j0 + 6) * 32 + h];
            const float o7 = ob[(size_t)(j0 + 7) * 32 + h];

            EDGE_FMA(o0, a0) EDGE_FMA(o1, a1) EDGE_FMA(o2, a2) EDGE_FMA(o3, a3)
            EDGE_FMA(o4, a4) EDGE_FMA(o5, a5) EDGE_FMA(o6, a6) EDGE_FMA(o7, a7)
        }
        if (j0 < dn) {                 // masked tail batch (addresses clamped)
            const int jm = dn - 1;
            const int j1 = min(j0 + 1, jm), j2 = min(j0 + 2, jm);
            const int j3 = min(j0 + 3, jm), j4 = min(j0 + 4, jm);
            const int j5 = min(j0 + 5, jm), j6 = min(j0 + 6, jm);
            const float4 a0 = *(const float4*)(eb + (size_t)j0 * 8 + f0);
            const float4 a1 = *(const float4*)(eb + (size_t)j1 * 8 + f0);
            const float4 a2 = *(const float4*)(eb + (size_t)j2 * 8 + f0);
            const float4 a3 = *(const float4*)(eb + (size_t)j3 * 8 + f0);
            const float4 a4 = *(const float4*)(eb + (size_t)j4 * 8 + f0);
            const float4 a5 = *(const float4*)(eb + (size_t)j5 * 8 + f0);
            const float4 a6 = *(const float4*)(eb + (size_t)j6 * 8 + f0);
            const float o0 = ob[(size_t)j0 * 32 + h];
            float o1 = ob[(size_t)j1 * 32 + h];
            float o2 = ob[(size_t)j2 * 32 + h];
            float o3 = ob[(size_t)j3 * 32 + h];
            float o4 = ob[(size_t)j4 * 32 + h];
            float o5 = ob[(size_t)j5 * 32 + h];
            float o6 = ob[(size_t)j6 * 32 + h];
            o1 = (j0 + 1 <= jm) ? o1 : 0.f;
            o2 = (j0 + 2 <= jm) ? o2 : 0.f;
            o3 = (j0 + 3 <= jm) ? o3 : 0.f;
            o4 = (j0 + 4 <= jm) ? o4 : 0.f;
            o5 = (j0 + 5 <= jm) ? o5 : 0.f;
            o6 = (j0 + 6 <= jm) ? o6 : 0.f;
            EDGE_FMA(o0, a0) EDGE_FMA(o1, a1) EDGE_FMA(o2, a2) EDGE_FMA(o3, a3)
            EDGE_FMA(o4, a4) EDGE_FMA(o5, a5) EDGE_FMA(o6, a6)
        }

        // Stage T (lane l -> T[d=h, f0..f0+3]), (S, out[n,d]) for the contraction.
        *(float4*)&s_T[w * 256 + h * 8 + f0] = make_float4(T0, T1, T2, T3);
        if (p == 0) s_SO[w * 32 + h] = make_float2(S, outn[(size_t)nu * DIMN + h]);
        // Same-wave LDS write->read: lockstep + compiler lgkmcnt orders this.

        const float base = aggfb[(size_t)nu * HD + h] + s_cb[h];

        // Contraction: lane (h,p) sums its 16-d half; 4 split accumulator chains.
        float acc0 = 0.f, acc1 = 0.f, acc2 = 0.f, acc3 = 0.f;
        const int d0 = p << 4;
        #pragma unroll
        for (int dd = 0; dd < 16; dd += 4) {
            CONTRIB(dd + 0, acc0)
            CONTRIB(dd + 1, acc1)
            CONTRIB(dd + 2, acc2)
            CONTRIB(dd + 3, acc3)
        }
        float acc = (acc0 + acc1) + (acc2 + acc3);
        acc += __shfl_xor(acc, 32);              // combine the two half-wave d-halves

        const float v = fmaxf(acc + base, 0.f);
        if (p == 0) s_V[w * 32 + h] = v;
        gval = batch[nu];                        // uniform across the wave
    }
    if (l == 0) s_G[w] = gval;
    __syncthreads();

    // Block-level run-length pool over the 16 consecutive nodes (batch sorted).
    if (tid < 32) {
        float accp = 0.f;
        int   gc   = -1;
        #pragma unroll
        for (int ww = 0; ww < K3W; ++ww) {
            const int gg = s_G[ww];
            if (gg >= 0) {
                const float vv = s_V[ww * 32 + tid];
                if (gg != gc) {
                    if (gc >= 0) atomicAdd(u + (size_t)gc * HD + tid, accp);
                    gc = gg;
                    accp = vv;
                } else {
                    accp += vv;
                }
            }
        }
        if (gc >= 0) atomicAdd(u + (size_t)gc * HD + tid, accp);
    }
}

// K4: head — o = relu(u@lin1_w^T + lin1_b); out = o@lin2_w^T + lin2_b.
__global__ __launch_bounds__(64) void k4_head(
    const float* __restrict__ u, const float* __restrict__ lin1_w,
    const float* __restrict__ lin1_b, const float* __restrict__ lin2_w,
    const float* __restrict__ lin2_b, float* __restrict__ outp)
{
    const int g = threadIdx.x;
    if (g >= NG) return;

    float ur[HD];
    #pragma unroll
    for (int hh = 0; hh < HD; ++hh) ur[hh] = u[(size_t)g * HD + hh];

    float acc = lin2_b[0];
    #pragma unroll
    for (int i = 0; i < 16; ++i) {
        float o = lin1_b[i];
        #pragma unroll
        for (int hh = 0; hh < HD; ++hh)
            o = fmaf(ur[hh], lin1_w[i * HD + hh], o);
        o = fmaxf(o, 0.f);
        acc = fmaf(o, lin2_w[i], acc);
    }
    outp[g] = acc;
}

extern "C" void kernel_launch(void* const* d_in, const int* in_sizes, int n_in,
                              void* d_out, int out_size, void* d_ws, size_t ws_size,
                              hipStream_t stream)
{
    const float* x      = (const float*)d_in[0];
    const int*   ei     = (const int*)  d_in[1];
    const float* ea     = (const float*)d_in[2];
    const int*   batch  = (const int*)  d_in[3];
    const float* lin0_w = (const float*)d_in[4];
    const float* lin0_b = (const float*)d_in[5];
    const float* nn_w   = (const float*)d_in[6];
    const float* nn_b   = (const float*)d_in[7];
    const float* root_w = (const float*)d_in[8];
    const float* conv_b = (const float*)d_in[9];
    const float* lin1_w = (const float*)d_in[10];
    const float* lin1_b = (const float*)d_in[11];
    const float* lin2_w = (const float*)d_in[12];
    const float* lin2_b = (const float*)d_in[13];

    const int N = in_sizes[0] / FN;   // 12500
    const int E = in_sizes[2] / FE;   // 200000

    float* ws    = (float*)d_ws;
    float* outB  = ws;                              // N*CAP*32 floats (102.4 MB)
    float* eaB   = outB + (size_t)N * CAP * 32;     // N*CAP*8  floats (25.6 MB)
    float* outn  = eaB  + (size_t)N * CAP * 8;      // N*32
    float* aggfb = outn + (size_t)N * DIMN;         // N*32 (overflow fallback)
    float* u     = aggfb + (size_t)N * DIMN;        // 64*32
    int*   deg   = (int*)(u + (size_t)NG * HD);     // N

    const int nb1 = (N * DIMN + 255) / 256;      // 1563
    k1_out<<<nb1, 256, 0, stream>>>(x, lin0_w, lin0_b, outn, aggfb, u, deg, N);

    const int nbb = ((size_t)E * 8 + 255) / 256; // 6250
    kb_bucket<<<nbb, 256, 0, stream>>>(ei, ea, outn, nn_w, nn_b, deg, eaB, outB,
                                       aggfb, E);

    const int nb3 = (N + K3W - 1) / K3W;         // 782 (16 nodes / block)
    k3_gather<<<nb3, K3T, 0, stream>>>(eaB, outB, outn, nn_w, nn_b, root_w, conv_b,
                                       deg, aggfb, batch, u, N);

    k4_head<<<1, 64, 0, stream>>>(u, lin1_w, lin1_b, lin2_w, lin2_b, (float*)d_out);
}

// Round 12
// 145.275 us; speedup vs baseline: 1.0944x; 1.0836x over previous
//
#include <hip/hip_runtime.h>

#define DIMN 32
#define HD   32
#define FN   16
#define FE   8
#define NG   64
#define CAP  64          // bucket capacity (in-degree ~Poisson(16); fallback below)
#define K3T  512
#define K3W  (K3T / 64)  // 8 waves; one node per wave per iteration
#define K3IT 2           // iterations per block -> 16 contiguous nodes/block
#define K3NPB (K3W * K3IT)

// K1: out = relu(x @ lin0_w^T + lin0_b); zero deg/aggfb/u.  (R5-proven)
__global__ __launch_bounds__(256) void k1_out(
    const float* __restrict__ x, const float* __restrict__ lin0_w,
    const float* __restrict__ lin0_b,
    float* __restrict__ outn, float* __restrict__ aggfb, float* __restrict__ u,
    int* __restrict__ deg, int N)
{
    const int gt = blockIdx.x * 256 + threadIdx.x;
    if (gt >= N * DIMN) return;
    const int n = gt >> 5, d = gt & 31;

    float s = lin0_b[d];
    const float* xr = x + (size_t)n * FN;
    const float* wr = lin0_w + d * FN;
    #pragma unroll
    for (int j = 0; j < FN; ++j) s = fmaf(xr[j], wr[j], s);
    outn[gt] = fmaxf(s, 0.f);

    aggfb[gt] = 0.f;
    if (d == 0) deg[n] = 0;
    if (gt < NG * HD) u[gt] = 0.f;
}

// Kb: bucket edges by destination: es[dst*CAP+pos] = {e, src}.  (R5-proven,
// index-only: 1.6 MB of writes, not the 128 MB value-staging experiment.)
// Overflow (statistically never for Poisson(16) vs CAP=64): compute the message
// directly and atomicAdd into aggfb, which K3 adds before relu.
__global__ __launch_bounds__(256) void kb_bucket(
    const int* __restrict__ ei, const float* __restrict__ ea,
    const float* __restrict__ outn, const float* __restrict__ nn_w,
    const float* __restrict__ nn_b,
    int* __restrict__ deg, int2* __restrict__ es, float* __restrict__ aggfb, int E)
{
    const int e = blockIdx.x * 256 + threadIdx.x;
    if (e >= E) return;
    const int src = ei[e];
    const int dst = ei[E + e];
    const int pos = atomicAdd(&deg[dst], 1);
    if (pos < CAP) {
        es[(size_t)dst * CAP + pos] = make_int2(e, src);
    } else {
        float ef[FE];
        #pragma unroll
        for (int f = 0; f < FE; ++f) ef[f] = ea[(size_t)e * FE + f];
        for (int h = 0; h < HD; ++h) {
            float m = 0.f;
            for (int d = 0; d < DIMN; ++d) {
                float wdh = nn_b[d * HD + h];
                #pragma unroll
                for (int f = 0; f < FE; ++f)
                    wdh = fmaf(ef[f], nn_w[(d * HD + h) * FE + f], wdh);
                m = fmaf(outn[(size_t)src * DIMN + d], wdh, m);
            }
            atomicAdd(aggfb + (size_t)dst * HD + h, m);
        }
    }
}

// One edge's contribution (mask already applied to o).
#define EDGE_FMA(o, a) \
    S  = (S + (o));                      \
    T0 = fmaf((o), (a).x, T0);           \
    T1 = fmaf((o), (a).y, T1);           \
    T2 = fmaf((o), (a).z, T2);           \
    T3 = fmaf((o), (a).w, T3);

// One d-slice of the contraction into accumulator A.
#define CONTRIB(DD, A) { \
    const int d_ = d0 + (DD); \
    const float4 ta_ = *(const float4*)&s_T[w * 256 + d_ * 8]; \
    const float4 tb_ = *(const float4*)&s_T[w * 256 + d_ * 8 + 4]; \
    const float2 so_ = s_SO[w * 32 + d_]; \
    const int b_ = d_ * 256 + h; \
    A = fmaf(ta_.x, s_nnw2[b_      ], A); \
    A = fmaf(ta_.y, s_nnw2[b_ +  32], A); \
    A = fmaf(ta_.z, s_nnw2[b_ +  64], A); \
    A = fmaf(ta_.w, s_nnw2[b_ +  96], A); \
    A = fmaf(tb_.x, s_nnw2[b_ + 128], A); \
    A = fmaf(tb_.y, s_nnw2[b_ + 160], A); \
    A = fmaf(tb_.z, s_nnw2[b_ + 192], A); \
    A = fmaf(tb_.w, s_nnw2[b_ + 224], A); \
    A = fmaf(so_.x, s_nnb[d_ * 32 + h], A); \
    A = fmaf(so_.y, s_rw [d_ * 32 + h], A); }

// K3: R5-proven body (chunk-8 edge loop: 8 uniform s_loads of {e,src} -> 16
// vector loads in flight -> FMAs; per-wave LDS T staging; conflict-free
// contraction) wrapped in a 2-iteration persistent loop: each block covers 16
// CONTIGUOUS nodes, staging the 40 KB of weights ONCE (1563 -> 782 stagings),
// and the run-length pool accumulator carries across iterations (u-atomics halve).
__global__ __launch_bounds__(K3T, 8) void k3_gather(
    const float* __restrict__ ea, const float* __restrict__ outn,
    const int2* __restrict__ es, const float* __restrict__ nn_w,
    const float* __restrict__ nn_b, const float* __restrict__ root_w,
    const float* __restrict__ conv_b, const int* __restrict__ deg,
    const float* __restrict__ aggfb, const int* __restrict__ batch,
    float* __restrict__ u, int N)
{
    __shared__ float  s_nnw2[DIMN * FE * HD];  // [(d*8+f)*32 + h]  32 KB
    __shared__ float  s_nnb[DIMN * HD];        // 4 KB
    __shared__ float  s_rw[DIMN * HD];         // 4 KB
    __shared__ float  s_cb[HD];
    __shared__ float  s_T[K3W * 256];          // 8 KB (per-wave T slot)
    __shared__ float2 s_SO[K3W * 32];          // 2 KB (S, out[n]) per wave
    __shared__ float  s_V[K3W * 32];           // 1 KB (per-wave node result)
    __shared__ int    s_G[K3W];

    const int tid = threadIdx.x;
    // Src-linear staging: coalesced global reads (known-fast R5 config; the LDS
    // write conflicts are cheaper than uncoalesced nn_w re-reads per block).
    for (int i = tid; i < DIMN * FE * HD; i += K3T) {
        const int d = i >> 8, rem = i & 255, hh = rem >> 3, f = rem & 7;
        s_nnw2[(d * 8 + f) * 32 + hh] = nn_w[i];   // nn_w[i] = nn_w[(d*32+hh)*8+f]
    }
    for (int i = tid; i < DIMN * HD; i += K3T) { s_nnb[i] = nn_b[i]; s_rw[i] = root_w[i]; }
    if (tid < HD) s_cb[tid] = conv_b[tid];
    __syncthreads();

    const int l = tid & 63;
    const int h = l & 31;
    const int p = l >> 5;
    const int w = tid >> 6;

    float accp  = 0.f;   // run-length pool state, carried across iterations
    int   g_cur = -1;    // (live in wave-0 lanes 0..31 for the pool phase)

    for (int it = 0; it < K3IT; ++it) {
        const int n = blockIdx.x * K3NPB + it * K3W + w;   // contiguous per block

        int gval = -1;
        if (n < N) {
            const int nu = __builtin_amdgcn_readfirstlane(n);
            const int dn = min(deg[nu], CAP);          // uniform -> s_load
            const int2* ep = es + (size_t)nu * CAP;
            const int f0 = 4 * p;

            float T0 = 0.f, T1 = 0.f, T2 = 0.f, T3 = 0.f, S = 0.f;

            for (int j0 = 0; j0 < dn; j0 += 8) {
                const int jm = dn - 1;
                // 8 uniform index loads (SGPR), clamped for the tail.
                const int2 E0 = ep[j0];
                const int2 E1 = ep[min(j0 + 1, jm)];
                const int2 E2 = ep[min(j0 + 2, jm)];
                const int2 E3 = ep[min(j0 + 3, jm)];
                const int2 E4 = ep[min(j0 + 4, jm)];
                const int2 E5 = ep[min(j0 + 5, jm)];
                const int2 E6 = ep[min(j0 + 6, jm)];
                const int2 E7 = ep[min(j0 + 7, jm)];

                // 16 independent vector loads, all in flight together.
                const float4 a0 = *(const float4*)(ea + (size_t)E0.x * FE + f0);
                const float4 a1 = *(const float4*)(ea + (size_t)E1.x * FE + f0);
                const float4 a2 = *(const float4*)(ea + (size_t)E2.x * FE + f0);
                const float4 a3 = *(const float4*)(ea + (size_t)E3.x * FE + f0);
                const float4 a4 = *(const float4*)(ea + (size_t)E4.x * FE + f0);
                const float4 a5 = *(const float4*)(ea + (size_t)E5.x * FE + f0);
                const float4 a6 = *(const float4*)(ea + (size_t)E6.x * FE + f0);
                const float4 a7 = *(const float4*)(ea + (size_t)E7.x * FE + f0);
                float o0 = outn[(size_t)E0.y * DIMN + h];
                float o1 = outn[(size_t)E1.y * DIMN + h];
                float o2 = outn[(size_t)E2.y * DIMN + h];
                float o3 = outn[(size_t)E3.y * DIMN + h];
                float o4 = outn[(size_t)E4.y * DIMN + h];
                float o5 = outn[(size_t)E5.y * DIMN + h];
                float o6 = outn[(size_t)E6.y * DIMN + h];
                float o7 = outn[(size_t)E7.y * DIMN + h];

                // Zero-mask clamped tail edges (uniform conditions -> cndmask).
                o1 = (j0 + 1 <= jm) ? o1 : 0.f;
                o2 = (j0 + 2 <= jm) ? o2 : 0.f;
                o3 = (j0 + 3 <= jm) ? o3 : 0.f;
                o4 = (j0 + 4 <= jm) ? o4 : 0.f;
                o5 = (j0 + 5 <= jm) ? o5 : 0.f;
                o6 = (j0 + 6 <= jm) ? o6 : 0.f;
                o7 = (j0 + 7 <= jm) ? o7 : 0.f;

                EDGE_FMA(o0, a0) EDGE_FMA(o1, a1) EDGE_FMA(o2, a2) EDGE_FMA(o3, a3)
                EDGE_FMA(o4, a4) EDGE_FMA(o5, a5) EDGE_FMA(o6, a6) EDGE_FMA(o7, a7)
            }

            // Stage T (lane l -> T[d=h, f0..f0+3]), (S, out[n,d]).
            *(float4*)&s_T[w * 256 + h * 8 + f0] = make_float4(T0, T1, T2, T3);
            if (p == 0) s_SO[w * 32 + h] = make_float2(S, outn[(size_t)nu * DIMN + h]);
            // Same-wave LDS write->read: lockstep + compiler lgkmcnt orders this.

            const float base = aggfb[(size_t)nu * HD + h] + s_cb[h];

            // Contraction: lane (h,p) sums its 16-d half; 4 split chains.
            float acc0 = 0.f, acc1 = 0.f, acc2 = 0.f, acc3 = 0.f;
            const int d0 = p << 4;
            #pragma unroll
            for (int dd = 0; dd < 16; dd += 4) {
                CONTRIB(dd + 0, acc0)
                CONTRIB(dd + 1, acc1)
                CONTRIB(dd + 2, acc2)
                CONTRIB(dd + 3, acc3)
            }
            float acc = (acc0 + acc1) + (acc2 + acc3);
            acc += __shfl_xor(acc, 32);          // combine the two half-wave d-halves

            const float v = fmaxf(acc + base, 0.f);
            if (p == 0) s_V[w * 32 + h] = v;
            gval = batch[nu];                    // uniform across the wave
        }
        if (l == 0) s_G[w] = gval;
        __syncthreads();

        // Block-level run-length pool over this iteration's 8 consecutive nodes
        // (batch sorted; block's nodes are contiguous across iterations).
        if (tid < 32) {
            #pragma unroll
            for (int ww = 0; ww < K3W; ++ww) {
                const int gg = s_G[ww];
                if (gg >= 0) {
                    const float vv = s_V[ww * 32 + tid];
                    if (gg != g_cur) {
                        if (g_cur >= 0) atomicAdd(u + (size_t)g_cur * HD + tid, accp);
                        g_cur = gg;
                        accp = vv;
                    } else {
                        accp += vv;
                    }
                }
            }
        }
        __syncthreads();   // protect s_V/s_G before the next iteration overwrites
    }
    if (tid < 32 && g_cur >= 0) atomicAdd(u + (size_t)g_cur * HD + tid, accp);
}

// K4: head — o = relu(u@lin1_w^T + lin1_b); out = o@lin2_w^T + lin2_b.
// Separate dispatch (R6-proven; fusing it regressed in R7).
__global__ __launch_bounds__(64) void k4_head(
    const float* __restrict__ u, const float* __restrict__ lin1_w,
    const float* __restrict__ lin1_b, const float* __restrict__ lin2_w,
    const float* __restrict__ lin2_b, float* __restrict__ outp)
{
    const int g = threadIdx.x;
    if (g >= NG) return;

    float ur[HD];
    #pragma unroll
    for (int hh = 0; hh < HD; ++hh) ur[hh] = u[(size_t)g * HD + hh];

    float acc = lin2_b[0];
    #pragma unroll
    for (int i = 0; i < 16; ++i) {
        float o = lin1_b[i];
        #pragma unroll
        for (int hh = 0; hh < HD; ++hh)
            o = fmaf(ur[hh], lin1_w[i * HD + hh], o);
        o = fmaxf(o, 0.f);
        acc = fmaf(o, lin2_w[i], acc);
    }
    outp[g] = acc;
}

extern "C" void kernel_launch(void* const* d_in, const int* in_sizes, int n_in,
                              void* d_out, int out_size, void* d_ws, size_t ws_size,
                              hipStream_t stream)
{
    const float* x      = (const float*)d_in[0];
    const int*   ei     = (const int*)  d_in[1];
    const float* ea     = (const float*)d_in[2];
    const int*   batch  = (const int*)  d_in[3];
    const float* lin0_w = (const float*)d_in[4];
    const float* lin0_b = (const float*)d_in[5];
    const float* nn_w   = (const float*)d_in[6];
    const float* nn_b   = (const float*)d_in[7];
    const float* root_w = (const float*)d_in[8];
    const float* conv_b = (const float*)d_in[9];
    const float* lin1_w = (const float*)d_in[10];
    const float* lin1_b = (const float*)d_in[11];
    const float* lin2_w = (const float*)d_in[12];
    const float* lin2_b = (const float*)d_in[13];

    const int N = in_sizes[0] / FN;   // 12500
    const int E = in_sizes[2] / FE;   // 200000

    float* ws    = (float*)d_ws;
    float* outn  = ws;                           // N*32
    float* aggfb = outn  + (size_t)N * DIMN;     // N*32 (overflow fallback)
    float* u     = aggfb + (size_t)N * DIMN;     // 64*32
    int*   deg   = (int*)(u + (size_t)NG * HD);  // N
    int2*  es    = (int2*)(deg + N);             // N*CAP int2 (8B-aligned)

    const int nb1 = (N * DIMN + 255) / 256;      // 1563
    k1_out<<<nb1, 256, 0, stream>>>(x, lin0_w, lin0_b, outn, aggfb, u, deg, N);

    const int nbb = (E + 255) / 256;             // 782
    kb_bucket<<<nbb, 256, 0, stream>>>(ei, ea, outn, nn_w, nn_b, deg, es, aggfb, E);

    const int nb3 = (N + K3NPB - 1) / K3NPB;     // 782 (16 contiguous nodes/block)
    k3_gather<<<nb3, K3T, 0, stream>>>(ea, outn, es, nn_w, nn_b, root_w, conv_b,
                                       deg, aggfb, batch, u, N);

    k4_head<<<1, 64, 0, stream>>>(u, lin1_w, lin1_b, lin2_w, lin2_b, (float*)d_out);
}